// Round 5
// baseline (25695.972 us; speedup 1.0000x reference)
//
#include <hip/hip_runtime.h>
#include <math.h>

#define TT 2048
#define NSTEP 2053   // 2048 + 4 pipeline fill + 1 linear drain

typedef _Float16 half2v __attribute__((ext_vector_type(2)));
typedef _Float16 half4v __attribute__((ext_vector_type(4)));
typedef _Float16 half8v __attribute__((ext_vector_type(8)));

#if defined(__has_builtin)
#if __has_builtin(__builtin_amdgcn_fdot2)
#define HAVE_FDOT2 1
#endif
#endif

__device__ __forceinline__ float fdot2f(half2v a, half2v b, float c) {
#ifdef HAVE_FDOT2
    return __builtin_amdgcn_fdot2(a, b, c, false);
#else
    return c + (float)a.x * (float)b.x + (float)a.y * (float)b.y;
#endif
}

__device__ __forceinline__ half2v h2at(half8v v, int m) {
    half2v r; r.x = v[2 * m]; r.y = v[2 * m + 1]; return r;
}

__device__ __forceinline__ float sigf(float x) { return 1.0f / (1.0f + __expf(-x)); }
__device__ __forceinline__ float tanh_f(float x) {
    float t = __expf(fminf(2.0f * x, 30.0f));
    return (t - 1.0f) / (t + 1.0f);
}

// ---- ws layout (bytes) ----
// [0, 262144)        board: half [2 parity][8 group][16 b][512]  (h index < 496 used)
// [262144, +1024)    flags: int [8 group][32 member], monotone step counters
#define FLAGS_OFF 262144
#define ZERO_F4   16448      // float4 count covering board+flags

// LDS strides (halves). All chosen with stride%64==32 -> adjacent rows land 16
// banks apart (2-way aliasing = free on CDNA4).
#define W1STR 288
#define W2STR 416
#define W3STR 224
#define W4STR 160
#define W5STR 96
#define XSTR  544

__global__ __launch_bounds__(256)
void prep_zero(float4* ws) {
    int idx = blockIdx.x * 256 + threadIdx.x;
    if (idx < ZERO_F4) ws[idx] = make_float4(0.f, 0.f, 0.f, 0.f);
}

// One layer slice: RG h-units, 4*RG gate rows (lr = rg + RG*i, gate i, unit rg).
// KG-way k-split, J jj-iters of 8k each. Holder lane (kg==0) owns c/h for
// (unit rg, batches bg*4..bg*4+3), writes fp16 h to b-major board.
template<int RG, int KG, int J, int KOFF, int WSTR, int HBASE, bool ISL1>
__device__ __forceinline__ void layer_step(
    const _Float16* __restrict__ W, const float* __restrict__ lbias,
    const _Float16* __restrict__ Xl, _Float16* __restrict__ bdst,
    const float* __restrict__ w1x, const float* __restrict__ xinL, int xoff,
    float* __restrict__ cpriv, int u, int bi)
{
    const int kg = u & (KG - 1);
    const int bg = (u / KG) & 3;
    const int rg = u / (KG * 4);

    float acc[4][4];
#pragma unroll
    for (int i = 0; i < 4; ++i)
#pragma unroll
        for (int j = 0; j < 4; ++j) acc[i][j] = 0.f;

#pragma unroll
    for (int jj = 0; jj < J; ++jj) {
        const int kk = kg * 8 + jj * (KG * 8);
        half8v xv[4], wv[4];
#pragma unroll
        for (int j = 0; j < 4; ++j)
            xv[j] = *(const half8v*)(Xl + (bg * 4 + j) * XSTR + KOFF + kk);
#pragma unroll
        for (int i = 0; i < 4; ++i)
            wv[i] = *(const half8v*)(W + (rg + RG * i) * WSTR + kk);
#pragma unroll
        for (int i = 0; i < 4; ++i)
#pragma unroll
            for (int j = 0; j < 4; ++j)
#pragma unroll
                for (int m = 0; m < 4; ++m)
                    acc[i][j] = fdot2f(h2at(wv[i], m), h2at(xv[j], m), acc[i][j]);
    }

#pragma unroll
    for (int d = 1; d < KG; d <<= 1)
#pragma unroll
        for (int i = 0; i < 4; ++i)
#pragma unroll
            for (int j = 0; j < 4; ++j)
                acc[i][j] += __shfl_xor(acc[i][j], d, 64);

    if (kg == 0) {
        const int hglob = HBASE + bi * RG + rg;
#pragma unroll
        for (int j = 0; j < 4; ++j) {
            float g0 = acc[0][j] + lbias[rg];
            float g1 = acc[1][j] + lbias[rg + RG];
            float g2 = acc[2][j] + lbias[rg + 2 * RG];
            float g3 = acc[3][j] + lbias[rg + 3 * RG];
            if (ISL1) {
                float xt = xinL[(bg * 4 + j) * 64 + xoff];
                g0 = fmaf(w1x[rg], xt, g0);
                g1 = fmaf(w1x[rg + RG], xt, g1);
                g2 = fmaf(w1x[rg + 2 * RG], xt, g2);
                g3 = fmaf(w1x[rg + 3 * RG], xt, g3);
            }
            float ig = sigf(g0), fg = sigf(g1), gg = tanh_f(g2), og = sigf(g3);
            float cn = fmaf(fg, cpriv[j], ig * gg);
            cpriv[j] = cn;
            bdst[(bg * 4 + j) * 512 + hglob] = (_Float16)(og * tanh_f(cn));
        }
    }
}

__global__ __launch_bounds__(512)
void lstm_pr(const float* __restrict__ inp,
             const float* __restrict__ w1ih, const float* __restrict__ w1hh,
             const float* __restrict__ b1ih, const float* __restrict__ b1hh,
             const float* __restrict__ w2ih, const float* __restrict__ w2hh,
             const float* __restrict__ b2ih, const float* __restrict__ b2hh,
             const float* __restrict__ w3ih, const float* __restrict__ w3hh,
             const float* __restrict__ b3ih, const float* __restrict__ b3hh,
             const float* __restrict__ w4ih, const float* __restrict__ w4hh,
             const float* __restrict__ b4ih, const float* __restrict__ b4hh,
             const float* __restrict__ w5ih, const float* __restrict__ w5hh,
             const float* __restrict__ b5ih, const float* __restrict__ b5hh,
             const float* __restrict__ wlin, const float* __restrict__ blin,
             float* __restrict__ out, char* __restrict__ wsb)
{
    __shared__ __align__(16) _Float16 Wl1[32 * W1STR];
    __shared__ __align__(16) _Float16 Wl2[16 * W2STR];
    __shared__ __align__(16) _Float16 Wl3[8 * W3STR];
    __shared__ __align__(16) _Float16 Wl4[4 * W4STR];
    __shared__ __align__(16) _Float16 Wl5[4 * W5STR];
    __shared__ __align__(16) _Float16 Xl[16 * XSTR];     // staged [b][h1|..|h5]
    __shared__ __align__(16) float Xin_l[16 * 64];       // input chunk [b][64 t]
    __shared__ float lbias1[32], lbias2[16], lbias3[8], lbias4[4], lbias5[4];
    __shared__ float w1x[32], wlin_s[16], blin_s;

    const int tid = threadIdx.x;
    const int grp = blockIdx.x & 7;
    const int bi  = blockIdx.x >> 3;

    // ---- init: stage weight slices fp32->fp16 into LDS ----
    for (int idx = tid; idx < 32 * 256; idx += 512) {           // L1 (w1hh)
        int lr = idx >> 8, k = idx & 255;
        int i = lr >> 3, rr = lr & 7;
        int g = i * 256 + bi * 8 + rr;
        Wl1[lr * W1STR + k] = (_Float16)w1hh[g * 256 + k];
    }
    for (int idx = tid; idx < 16 * 384; idx += 512) {           // L2
        int lr = idx / 384, k = idx - lr * 384;
        int i = lr >> 2, rr = lr & 3;
        int g = i * 128 + bi * 4 + rr;
        float v = (k < 256) ? w2ih[g * 256 + k] : w2hh[g * 128 + (k - 256)];
        Wl2[lr * W2STR + k] = (_Float16)v;
    }
    for (int idx = tid; idx < 8 * 192; idx += 512) {            // L3
        int lr = idx / 192, k = idx - lr * 192;
        int i = lr >> 1, rr = lr & 1;
        int g = i * 64 + bi * 2 + rr;
        float v = (k < 128) ? w3ih[g * 128 + k] : w3hh[g * 64 + (k - 128)];
        Wl3[lr * W3STR + k] = (_Float16)v;
    }
    for (int idx = tid; idx < 4 * 96; idx += 512) {             // L4
        int lr = idx / 96, k = idx - lr * 96;
        int g = lr * 32 + bi;
        float v = (k < 64) ? w4ih[g * 64 + k] : w4hh[g * 32 + (k - 64)];
        Wl4[lr * W4STR + k] = (_Float16)v;
    }
    if (bi < 16)
        for (int idx = tid; idx < 4 * 48; idx += 512) {         // L5
            int lr = idx / 48, k = idx - lr * 48;
            int g = lr * 16 + bi;
            float v = (k < 32) ? w5ih[g * 32 + k] : w5hh[g * 16 + (k - 32)];
            Wl5[lr * W5STR + k] = (_Float16)v;
        }
    if (tid < 32) {
        int i = tid >> 3, rr = tid & 7;
        int g = i * 256 + bi * 8 + rr;
        lbias1[tid] = b1ih[g] + b1hh[g];
        w1x[tid] = w1ih[g];
    } else if (tid < 48) {
        int u = tid - 32; int i = u >> 2, rr = u & 3;
        int g = i * 128 + bi * 4 + rr;
        lbias2[u] = b2ih[g] + b2hh[g];
    } else if (tid < 56) {
        int u = tid - 48; int i = u >> 1, rr = u & 1;
        int g = i * 64 + bi * 2 + rr;
        lbias3[u] = b3ih[g] + b3hh[g];
    } else if (tid < 60) {
        int i = tid - 56; int g = i * 32 + bi;
        lbias4[i] = b4ih[g] + b4hh[g];
    } else if (tid < 64) {
        if (bi < 16) { int i = tid - 60; int g = i * 16 + bi; lbias5[i] = b5ih[g] + b5hh[g]; }
    } else if (tid < 80) {
        wlin_s[tid - 64] = wlin[tid - 64];
    } else if (tid == 80) {
        blin_s = blin[0];
    }
    __syncthreads();

    float cpriv[4] = {0.f, 0.f, 0.f, 0.f};
    _Float16* board = (_Float16*)wsb;
    int* flags = (int*)(wsb + FLAGS_OFF);

    for (int s = 0; s < NSTEP; ++s) {
        const int pr = (s + 1) & 1, pw = s & 1;

        // ---- stage X from b-major board: wave reads 1 KB contiguous ----
        const _Float16* bsrc = board + (size_t)((pr * 8 + grp) * 16) * 512;
#pragma unroll
        for (int it = 0; it < 2; ++it) {
            int i = tid + it * 512;          // 16B chunk id, 64 chunks per b-row
            int b = i >> 6;
            int h8 = (i & 63) << 3;
            *(half8v*)(Xl + b * XSTR + h8) = *(const half8v*)(bsrc + b * 512 + h8);
        }
        if ((s & 63) == 0 && s < TT && tid < 256) {
            int b = tid >> 4, t4 = (tid & 15) << 2;
            *(float4*)(Xin_l + b * 64 + t4) =
                *(const float4*)(inp + (size_t)(grp * 16 + b) * TT + s + t4);
        }
        __syncthreads();

        _Float16* bdst = board + (size_t)((pw * 8 + grp) * 16) * 512;
        const int xoff = s & 63;

        if (tid < 128) {
            if (s <= 2047)
                layer_step<8, 4, 8, 0, W1STR, 0, true >(Wl1, lbias1, Xl, bdst, w1x, Xin_l, xoff, cpriv, tid, bi);
        } else if (tid < 256) {
            if (s >= 1 && s <= 2048)
                layer_step<4, 8, 6, 0, W2STR, 256, false>(Wl2, lbias2, Xl, bdst, w1x, Xin_l, xoff, cpriv, tid - 128, bi);
        } else if (tid < 320) {
            if (s >= 2 && s <= 2049)
                layer_step<2, 8, 3, 256, W3STR, 384, false>(Wl3, lbias3, Xl, bdst, w1x, Xin_l, xoff, cpriv, tid - 256, bi);
        } else if (tid < 336) {
            if (s >= 3 && s <= 2050)
                layer_step<1, 4, 3, 384, W4STR, 448, false>(Wl4, lbias4, Xl, bdst, w1x, Xin_l, xoff, cpriv, tid - 320, bi);
        } else if (tid < 344) {
            if (bi < 16 && s >= 4 && s <= 2051)
                layer_step<1, 2, 3, 448, W5STR, 480, false>(Wl5, lbias5, Xl, bdst, w1x, Xin_l, xoff, cpriv, tid - 336, bi);
        } else if (tid >= 416 && tid < 432) {
            if (bi == 31 && s >= 5) {
                int b = tid - 416;
                float a = blin_s;
#pragma unroll
                for (int j = 0; j < 16; ++j)
                    a += (float)Xl[b * XSTR + 480 + j] * wlin_s[j];
                out[(size_t)(grp * 16 + b) * TT + (s - 5)] = a;
            }
        }

        // ---- group barrier: per-block monotone flag + parallel poll ----
        __syncthreads();   // all waves' board writes drained (vmcnt(0) at barrier)
        if (tid < 64) {
            if (tid == 0)
                __hip_atomic_store(flags + grp * 32 + bi, s + 1,
                                   __ATOMIC_RELEASE, __HIP_MEMORY_SCOPE_AGENT);
            int* fp = flags + grp * 32 + (tid & 31);
            while (__hip_atomic_load(fp, __ATOMIC_RELAXED,
                                     __HIP_MEMORY_SCOPE_AGENT) <= s)
                __builtin_amdgcn_s_sleep(1);
            __builtin_amdgcn_fence(__ATOMIC_ACQUIRE, "agent");
        }
        __syncthreads();
    }
}

extern "C" void kernel_launch(void* const* d_in, const int* in_sizes, int n_in,
                              void* d_out, int out_size, void* d_ws, size_t ws_size,
                              hipStream_t stream) {
    const float* p[23];
    for (int i = 0; i < 23 && i < n_in; ++i) p[i] = (const float*)d_in[i];

    prep_zero<<<dim3((ZERO_F4 + 255) / 256), dim3(256), 0, stream>>>((float4*)d_ws);

    // ~59 KB static + 32 KB dynamic -> 91 KB/block -> 1 block/CU, grid 256 = CU
    // count -> all blocks co-resident (required for the flag barrier).
    lstm_pr<<<dim3(256), dim3(512), 32768, stream>>>(
        p[0],
        p[1],  p[2],  p[3],  p[4],
        p[5],  p[6],  p[7],  p[8],
        p[9],  p[10], p[11], p[12],
        p[13], p[14], p[15], p[16],
        p[17], p[18], p[19], p[20],
        p[21], p[22],
        (float*)d_out, (char*)d_ws);
}